// Round 6
// baseline (352.595 us; speedup 1.0000x reference)
//
#include <hip/hip_runtime.h>
#include <hip/hip_bf16.h>

// GCN_20332375179669: 2-layer graph attention, B=8 N=2048 H=256 A=64.
// R6: plain kernels (R5's cooperative launch silently failed). csr build is
// split: K1 = pack+embed+csr[0,6144), K2 = qkv-1 MFMA + csr[6144,16384) so
// the qkv GEMM hides under the HBM-bound adj stream. Attention batches all
// gathers per 16-edge chunk (1 round-trip per chunk), dot2/perm packed math.

#define NB 8
#define NN 2048
#define ROWS (NB * NN)
#define MAXD 64     // Binomial(2048,0.01): mean 20.5, sd 4.5 -> ~9.7 sigma
#define CSR1 6144   // csr rows scanned in K1; rest in K2

typedef float f4 __attribute__((ext_vector_type(4)));
typedef _Float16 hf;
typedef _Float16 hx2 __attribute__((ext_vector_type(2)));
typedef _Float16 hx4 __attribute__((ext_vector_type(4)));
typedef _Float16 hx8 __attribute__((ext_vector_type(8)));
typedef unsigned int u32;
typedef unsigned short u16;
typedef u16 us8 __attribute__((ext_vector_type(8)));

__device__ __forceinline__ float sigmoidf_(float x) { return 1.f / (1.f + __expf(-x)); }
__device__ __forceinline__ hx2 u2h(u32 u) { union { u32 u; hx2 h; } c; c.u = u; return c.h; }
__device__ __forceinline__ float dot2_(hx2 a, hx2 b, float c) {
#if __has_builtin(__builtin_amdgcn_fdot2)
    return __builtin_amdgcn_fdot2(a, b, c, false);
#else
    return c + (float)a.x * (float)b.x + (float)a.y * (float)b.y;
#endif
}
// (lo.f16_0, hi.f16_0) / (lo.f16_1, hi.f16_1)
__device__ __forceinline__ u32 permlo_(u32 hi, u32 lo) { return __builtin_amdgcn_perm(hi, lo, 0x05040100u); }
__device__ __forceinline__ u32 permhi_(u32 hi, u32 lo) { return __builtin_amdgcn_perm(hi, lo, 0x07060302u); }

// ---- csr scan of one adjacency row (2048 floats, f4 NT loads)
__device__ __forceinline__ void csr_row(const float* __restrict__ adj,
                                        int* __restrict__ deg, int* __restrict__ nbr,
                                        int row, int t, int* cnt) {
    const f4* ar4 = (const f4*)(adj + (size_t)row * NN);
    if (t == 0) *cnt = 0;
    __syncthreads();
    int* nr = nbr + (size_t)row * MAXD;
#pragma unroll
    for (int it = 0; it < 2; ++it) {
        int idx = it * 256 + t;
        f4 vv = __builtin_nontemporal_load(ar4 + idx);
        if (vv.x > 0.f) { int p = atomicAdd(cnt, 1); if (p < MAXD) nr[p] = idx * 4 + 0; }
        if (vv.y > 0.f) { int p = atomicAdd(cnt, 1); if (p < MAXD) nr[p] = idx * 4 + 1; }
        if (vv.z > 0.f) { int p = atomicAdd(cnt, 1); if (p < MAXD) nr[p] = idx * 4 + 2; }
        if (vv.w > 0.f) { int p = atomicAdd(cnt, 1); if (p < MAXD) nr[p] = idx * 4 + 3; }
    }
    __syncthreads();
    if (t == 0) deg[row] = (*cnt < MAXD) ? *cnt : MAXD;
}

// ================================================================= K1
// bid < 512            : embed GEMM tile (fp32 compute, fp16 out)
// 512 <= bid < 608     : pack Wq|Wk|Wv -> Wpt[c][f] fp16 transposed
// bid >= 608           : csr rows [0, CSR1)
__global__ __launch_bounds__(256) void k_front1(
        const int* __restrict__ x, const int* __restrict__ cue,
        const float* __restrict__ adj, const float* __restrict__ emb,
        const float* __restrict__ Wh, const float* __restrict__ bh,
        const float* __restrict__ Wq, const float* __restrict__ Wk,
        const float* __restrict__ Wv,
        hf* __restrict__ hB, hf* __restrict__ Wpt,
        int* __restrict__ deg, int* __restrict__ nbr) {
    __shared__ float As[32 * 64];
    __shared__ float Ws[32 * 128];
    int bid = blockIdx.x;
    int t = threadIdx.x;

    if (bid < 512) {
        int row0 = (bid >> 1) * 64, col0 = (bid & 1) * 128;
        int srow = t & 63, skg = t >> 6;
        int swc = (t & 31) * 4, swk = t >> 5;
        int tx = t & 15, ty = t >> 4;
        int xr = x[row0 + srow];
        float cv = (float)cue[row0 + srow];
        const float* er = emb + (size_t)xr * 255;

        float acc[4][8];
#pragma unroll
        for (int i = 0; i < 4; ++i)
#pragma unroll
            for (int j = 0; j < 8; ++j) acc[i][j] = 0.f;

        for (int kc = 0; kc < 256; kc += 32) {
            int kb = skg * 8;
#pragma unroll
            for (int u = 0; u < 8; ++u) {
                int f = kc + kb + u;
                As[(kb + u) * 64 + srow] = (f < 255) ? er[f] : cv;
            }
#pragma unroll
            for (int r = 0; r < 4; ++r) {
                int kk = swk + r * 8;
                f4 w = *(const f4*)(Wh + (size_t)(kc + kk) * 256 + col0 + swc);
                *(f4*)&Ws[kk * 128 + swc] = w;
            }
            __syncthreads();
#pragma unroll
            for (int k = 0; k < 32; ++k) {
                f4 av = *(f4*)&As[k * 64 + ty * 4];
                f4 w0 = *(f4*)&Ws[k * 128 + tx * 8];
                f4 w1 = *(f4*)&Ws[k * 128 + tx * 8 + 4];
                float a[4] = {av.x, av.y, av.z, av.w};
                float w[8] = {w0.x, w0.y, w0.z, w0.w, w1.x, w1.y, w1.z, w1.w};
#pragma unroll
                for (int i = 0; i < 4; ++i)
#pragma unroll
                    for (int j = 0; j < 8; ++j) acc[i][j] += a[i] * w[j];
            }
            __syncthreads();
        }
        f4 b0 = *(const f4*)(bh + col0 + tx * 8);
        f4 b1 = *(const f4*)(bh + col0 + tx * 8 + 4);
        float bb[8] = {b0.x, b0.y, b0.z, b0.w, b1.x, b1.y, b1.z, b1.w};
#pragma unroll
        for (int i = 0; i < 4; ++i) {
            int row = row0 + ty * 4 + i;
            hx8 o;
#pragma unroll
            for (int j = 0; j < 8; ++j) o[j] = (hf)fmaxf(acc[i][j] + bb[j], 0.f);
            *(hx8*)(hB + (size_t)row * 256 + col0 + tx * 8) = o;
        }
        return;
    }

    if (bid < 608) {
        int base = (bid - 512) * 256 + t;
#pragma unroll
        for (int r = 0; r < 4; ++r) {
            int i = base + r * 96 * 256;
            int c = i >> 8, f = i & 255;
            float v;
            if (c < 64)       v = Wq[f * 64 + c];
            else if (c < 128) v = Wk[f * 64 + (c - 64)];
            else              v = Wv[f * 256 + (c - 128)];
            Wpt[i] = (hf)v;
        }
        return;
    }

    csr_row(adj, deg, nbr, bid - 608, t, (int*)As);
}

// ================================================================= K2
// bid < 768 : qkv layer-1 MFMA tile (64x128, LDS-staged) — hidden under csr
// bid >= 768: csr rows [CSR1, 16384)
union QSMem {
    struct { u16 As[64 * 40]; u16 Bs[128 * 40]; } q;   // 15360 B
    int cnt;
};

__device__ __forceinline__ void qkv_tile(const hf* __restrict__ hB,
                                         const hf* __restrict__ Wpt,
                                         hf* __restrict__ qkvB,
                                         int tile, int t, QSMem& sm) {
    int col0 = (tile % 3) * 128, row0 = (tile / 3) * 64;
    int wave = t >> 6, lane = t & 63;
    int l16 = lane & 15, quad = lane >> 4;
    f4 acc[4][2];
#pragma unroll
    for (int i = 0; i < 4; ++i) { acc[i][0] = (f4){0,0,0,0}; acc[i][1] = (f4){0,0,0,0}; }
    int ar = t >> 2, ao = (t & 3) * 8;
    int bcs = t >> 1, bo = (t & 1) * 16;
    const u16* hB16 = (const u16*)hB;
    const u16* Wp16 = (const u16*)Wpt;

    for (int kc = 0; kc < 256; kc += 32) {
        us8 av  = *(const us8*)(hB16 + (size_t)(row0 + ar) * 256 + kc + ao);
        us8 bv0 = *(const us8*)(Wp16 + (size_t)(col0 + bcs) * 256 + kc + bo);
        us8 bv1 = *(const us8*)(Wp16 + (size_t)(col0 + bcs) * 256 + kc + bo + 8);
        __syncthreads();               // prior iter frag reads done
        *(us8*)&sm.q.As[ar * 40 + ao] = av;
        *(us8*)&sm.q.Bs[bcs * 40 + bo] = bv0;
        *(us8*)&sm.q.Bs[bcs * 40 + bo + 8] = bv1;
        __syncthreads();
        hx8 afr[4], bfr[2];
#pragma unroll
        for (int mt = 0; mt < 4; ++mt)
            afr[mt] = *(hx8*)&sm.q.As[(mt * 16 + l16) * 40 + quad * 8];
#pragma unroll
        for (int nt = 0; nt < 2; ++nt)
            bfr[nt] = *(hx8*)&sm.q.Bs[((wave * 2 + nt) * 16 + l16) * 40 + quad * 8];
#pragma unroll
        for (int mt = 0; mt < 4; ++mt)
#pragma unroll
            for (int nt = 0; nt < 2; ++nt)
                acc[mt][nt] = __builtin_amdgcn_mfma_f32_16x16x32_f16(
                    afr[mt], bfr[nt], acc[mt][nt], 0, 0, 0);
    }
#pragma unroll
    for (int mt = 0; mt < 4; ++mt)
#pragma unroll
        for (int nt = 0; nt < 2; ++nt) {
            int c = col0 + (wave * 2 + nt) * 16 + l16;
#pragma unroll
            for (int reg = 0; reg < 4; ++reg) {
                int r = row0 + mt * 16 + quad * 4 + reg;
                qkvB[(size_t)r * 384 + c] = (hf)acc[mt][nt][reg];
            }
        }
}

__global__ __launch_bounds__(256) void k_qkv_csr(const hf* __restrict__ hB,
                                                 const hf* __restrict__ Wpt,
                                                 hf* __restrict__ qkvB,
                                                 const float* __restrict__ adj,
                                                 int* __restrict__ deg,
                                                 int* __restrict__ nbr) {
    __shared__ QSMem sm;
    int bid = blockIdx.x, t = threadIdx.x;
    if (bid < 768) qkv_tile(hB, Wpt, qkvB, bid, t, sm);
    else           csr_row(adj, deg, nbr, CSR1 + (bid - 768), t, &sm.cnt);
}

// ---- qkv layer 2 (pure)
__global__ __launch_bounds__(256) void k_qkv(const hf* __restrict__ hB,
                                             const hf* __restrict__ Wpt,
                                             hf* __restrict__ qkvB) {
    __shared__ QSMem sm;
    qkv_tile(hB, Wpt, qkvB, blockIdx.x, threadIdx.x, sm);
}

// ========================================================= sparse attention
// One wave per row; nbr list register-staged; per 16-edge chunk, ALL k and v
// gathers issued before dependent math (~1 round-trip/chunk). dot2/perm math.
// Grid XCD-swizzled: bid&7 = batch.
template <bool WRITE_OUT>
__global__ __launch_bounds__(256) void k_attn(const hf* __restrict__ qkvB,
                                              const int* __restrict__ deg,
                                              const int* __restrict__ nbr,
                                              const float* __restrict__ gcb,
                                              const float* __restrict__ Wc,
                                              const float* __restrict__ bc,
                                              hf* __restrict__ hB,
                                              float* __restrict__ out) {
    int wave = threadIdx.x >> 6;
    int lane = threadIdx.x & 63;
    int bid = blockIdx.x;
    int row = (bid & 7) * NN + (bid >> 3) * 4 + wave;
    int d = deg[row];
    int l16 = lane & 15, quad = lane >> 4;
    f4 g4 = *(const f4*)(gcb + lane * 4);
    float h0, h1, h2c, h3;
    if (d == 0) {
        h0 = sigmoidf_(g4.x); h1 = sigmoidf_(g4.y);
        h2c = sigmoidf_(g4.z); h3 = sigmoidf_(g4.w);
    } else {
        uint2 qq = *(const uint2*)(qkvB + (size_t)row * 384 + l16 * 4);
        hx2 q01 = u2h(qq.x), q23 = u2h(qq.y);
        int jlane = nbr[(size_t)row * MAXD + lane];
        int bbase = row & ~(NN - 1);
        float m = -1e30f, s = 0.f;
        f4 a = {0, 0, 0, 0};
        for (int e0 = 0; e0 < d; e0 += 16) {
            int jr[4]; uint2 kqr[4]; uint2 vr[4][4];
#pragma unroll
            for (int g = 0; g < 4; ++g) {
                if (e0 + g * 4 < d) {
                    int idx = e0 + g * 4 + quad;
                    jr[g] = __shfl(jlane, idx < d ? idx : 0);
                    kqr[g] = *(const uint2*)(qkvB + (size_t)(bbase + jr[g]) * 384 + 64 + l16 * 4);
                }
            }
#pragma unroll
            for (int g = 0; g < 4; ++g) {
                if (e0 + g * 4 < d) {
                    int j0 = __shfl(jr[g], 0),  j1 = __shfl(jr[g], 16);
                    int j2 = __shfl(jr[g], 32), j3 = __shfl(jr[g], 48);
                    vr[g][0] = *(const uint2*)(qkvB + (size_t)(bbase + j0) * 384 + 128 + lane * 4);
                    vr[g][1] = *(const uint2*)(qkvB + (size_t)(bbase + j1) * 384 + 128 + lane * 4);
                    vr[g][2] = *(const uint2*)(qkvB + (size_t)(bbase + j2) * 384 + 128 + lane * 4);
                    vr[g][3] = *(const uint2*)(qkvB + (size_t)(bbase + j3) * 384 + 128 + lane * 4);
                }
            }
            float pg[4];
#pragma unroll
            for (int g = 0; g < 4; ++g) {
                if (e0 + g * 4 < d) {
                    float p = dot2_(u2h(kqr[g].x), q01, dot2_(u2h(kqr[g].y), q23, 0.f));
                    p += __shfl_xor(p, 1); p += __shfl_xor(p, 2);
                    p += __shfl_xor(p, 4); p += __shfl_xor(p, 8);
                    int idx = e0 + g * 4 + quad;
                    pg[g] = (idx < d) ? p : -1e30f;
                } else pg[g] = -1e30f;
            }
            float cm = fmaxf(fmaxf(pg[0], pg[1]), fmaxf(pg[2], pg[3]));
            cm = fmaxf(cm, __shfl_xor(cm, 16));
            cm = fmaxf(cm, __shfl_xor(cm, 32));
            float mn = fmaxf(m, cm);
            float sc = __expf(m - mn);      // first chunk: exp(-inf) = 0
            s *= sc; a.x *= sc; a.y *= sc; a.z *= sc; a.w *= sc;
            m = mn;
#pragma unroll
            for (int g = 0; g < 4; ++g) {
                if (e0 + g * 4 < d) {
                    float w = __expf(pg[g] - mn);
                    float sw = w + __shfl_xor(w, 16);
                    sw = sw + __shfl_xor(sw, 32);
                    s += sw;
                    float w0 = __shfl(w, 0),  w1 = __shfl(w, 16);
                    float w2 = __shfl(w, 32), w3 = __shfl(w, 48);
                    hx2 w01, w23;
                    w01.x = (hf)w0; w01.y = (hf)w1;
                    w23.x = (hf)w2; w23.y = (hf)w3;
                    a.x = dot2_(u2h(permlo_(vr[g][1].x, vr[g][0].x)), w01,
                          dot2_(u2h(permlo_(vr[g][3].x, vr[g][2].x)), w23, a.x));
                    a.y = dot2_(u2h(permhi_(vr[g][1].x, vr[g][0].x)), w01,
                          dot2_(u2h(permhi_(vr[g][3].x, vr[g][2].x)), w23, a.y));
                    a.z = dot2_(u2h(permlo_(vr[g][1].y, vr[g][0].y)), w01,
                          dot2_(u2h(permlo_(vr[g][3].y, vr[g][2].y)), w23, a.z));
                    a.w = dot2_(u2h(permhi_(vr[g][1].y, vr[g][0].y)), w01,
                          dot2_(u2h(permhi_(vr[g][3].y, vr[g][2].y)), w23, a.w));
                }
            }
        }
        float inv = 1.f / s;
        h0 = sigmoidf_(a.x * inv + g4.x);
        h1 = sigmoidf_(a.y * inv + g4.y);
        h2c = sigmoidf_(a.z * inv + g4.z);
        h3 = sigmoidf_(a.w * inv + g4.w);
    }
    if (!WRITE_OUT) {
        hx4 o; o.x = (hf)h0; o.y = (hf)h1; o.z = (hf)h2c; o.w = (hf)h3;
        *(hx4*)(hB + (size_t)row * 256 + lane * 4) = o;
    } else {
        f4 wc0 = *(const f4*)(Wc + lane * 8);
        f4 wc1 = *(const f4*)(Wc + lane * 8 + 4);
        float pa = h0 * wc0.x + h1 * wc0.z + h2c * wc1.x + h3 * wc1.z;
        float pb = h0 * wc0.y + h1 * wc0.w + h2c * wc1.y + h3 * wc1.w;
#pragma unroll
        for (int off = 32; off; off >>= 1) {
            pa += __shfl_xor(pa, off);
            pb += __shfl_xor(pb, off);
        }
        if (lane == 0) {
            float l0 = pa + bc[0], l1 = pb + bc[1];
            float mx = fmaxf(l0, l1);
            float e0 = __expf(l0 - mx), e1 = __expf(l1 - mx);
            float inv2 = 1.f / (e0 + e1);
            out[(size_t)row * 2 + 0] = e0 * inv2;
            out[(size_t)row * 2 + 1] = e1 * inv2;
        }
    }
}

extern "C" void kernel_launch(void* const* d_in, const int* in_sizes, int n_in,
                              void* d_out, int out_size, void* d_ws, size_t ws_size,
                              hipStream_t stream) {
    const int*   x    = (const int*)d_in[0];
    const int*   cue  = (const int*)d_in[1];
    const float* adj  = (const float*)d_in[2];
    const float* emb  = (const float*)d_in[3];
    const float* Wh   = (const float*)d_in[4];
    const float* bh   = (const float*)d_in[5];
    const float* Wq   = (const float*)d_in[6];
    const float* Wk   = (const float*)d_in[7];
    const float* Wv   = (const float*)d_in[8];
    const float* gcb  = (const float*)d_in[9];
    const float* Wc   = (const float*)d_in[10];
    const float* bc   = (const float*)d_in[11];
    float* out = (float*)d_out;

    // workspace carve (~24.3 MB)
    char* w = (char*)d_ws;
    hf*  hB   = (hf*)w;   w += (size_t)ROWS * 256 * 2;   // 8 MB
    hf*  qkvB = (hf*)w;   w += (size_t)ROWS * 384 * 2;   // 12 MB
    hf*  Wpt  = (hf*)w;   w += (size_t)384 * 256 * 2;    // 192 KB
    int* deg  = (int*)w;  w += (size_t)ROWS * 4;         // 64 KB
    int* nbr  = (int*)w;                                  // 4 MB

    // K1: embed + pack + csr[0,CSR1)
    k_front1<<<608 + CSR1, 256, 0, stream>>>(
        x, cue, adj, emb, Wh, bh, Wq, Wk, Wv, hB, Wpt, deg, nbr);
    // K2: qkv layer 1 (hidden under csr[CSR1,16384))
    k_qkv_csr<<<768 + (ROWS - CSR1), 256, 0, stream>>>(hB, Wpt, qkvB, adj, deg, nbr);
    // K3: attn layer 1
    k_attn<false><<<ROWS / 4, 256, 0, stream>>>(qkvB, deg, nbr, gcb, Wc, bc, hB, out);
    // K4: qkv layer 2
    k_qkv<<<768, 256, 0, stream>>>(hB, Wpt, qkvB);
    // K5: attn layer 2 + classifier head
    k_attn<true><<<ROWS / 4, 256, 0, stream>>>(qkvB, deg, nbr, gcb, Wc, bc, hB, out);
}

// Round 7
// 342.225 us; speedup vs baseline: 1.0303x; 1.0303x over previous
//
#include <hip/hip_runtime.h>
#include <hip/hip_bf16.h>

// GCN_20332375179669: 2-layer graph attention, B=8 N=2048 H=256 A=64.
// R7: R6 structure (csr split across K1/K2, qkv1 hidden under adj stream) +
// rewritten attention: quad-per-edge logit pass, EXACT softmax (no online
// rescale), pre-normalized weights, fully-independent v-gather loop.
// ~3 memory round trips per row vs ~5-10, and low VGPR pressure (R6's
// chunked attn held 44+ VGPRs of gather data live -> occupancy collapse).

#define NB 8
#define NN 2048
#define ROWS (NB * NN)
#define MAXD 64     // Binomial(2048,0.01): mean 20.5, sd 4.5 -> ~9.7 sigma
#define CSR1 6144   // csr rows scanned in K1; rest in K2

typedef float f4 __attribute__((ext_vector_type(4)));
typedef _Float16 hf;
typedef _Float16 hx2 __attribute__((ext_vector_type(2)));
typedef _Float16 hx4 __attribute__((ext_vector_type(4)));
typedef _Float16 hx8 __attribute__((ext_vector_type(8)));
typedef unsigned int u32;
typedef unsigned short u16;
typedef u16 us8 __attribute__((ext_vector_type(8)));

__device__ __forceinline__ float sigmoidf_(float x) { return 1.f / (1.f + __expf(-x)); }
__device__ __forceinline__ hx2 u2h(u32 u) { union { u32 u; hx2 h; } c; c.u = u; return c.h; }
__device__ __forceinline__ float dot2_(hx2 a, hx2 b, float c) {
#if __has_builtin(__builtin_amdgcn_fdot2)
    return __builtin_amdgcn_fdot2(a, b, c, false);
#else
    return c + (float)a.x * (float)b.x + (float)a.y * (float)b.y;
#endif
}
// (lo.f16_0, hi.f16_0) / (lo.f16_1, hi.f16_1)
__device__ __forceinline__ u32 permlo_(u32 hi, u32 lo) { return __builtin_amdgcn_perm(hi, lo, 0x05040100u); }
__device__ __forceinline__ u32 permhi_(u32 hi, u32 lo) { return __builtin_amdgcn_perm(hi, lo, 0x07060302u); }

// ---- csr scan of one adjacency row (2048 floats, f4 NT loads)
__device__ __forceinline__ void csr_row(const float* __restrict__ adj,
                                        int* __restrict__ deg, int* __restrict__ nbr,
                                        int row, int t, int* cnt) {
    const f4* ar4 = (const f4*)(adj + (size_t)row * NN);
    if (t == 0) *cnt = 0;
    __syncthreads();
    int* nr = nbr + (size_t)row * MAXD;
#pragma unroll
    for (int it = 0; it < 2; ++it) {
        int idx = it * 256 + t;
        f4 vv = __builtin_nontemporal_load(ar4 + idx);
        if (vv.x > 0.f) { int p = atomicAdd(cnt, 1); if (p < MAXD) nr[p] = idx * 4 + 0; }
        if (vv.y > 0.f) { int p = atomicAdd(cnt, 1); if (p < MAXD) nr[p] = idx * 4 + 1; }
        if (vv.z > 0.f) { int p = atomicAdd(cnt, 1); if (p < MAXD) nr[p] = idx * 4 + 2; }
        if (vv.w > 0.f) { int p = atomicAdd(cnt, 1); if (p < MAXD) nr[p] = idx * 4 + 3; }
    }
    __syncthreads();
    if (t == 0) deg[row] = (*cnt < MAXD) ? *cnt : MAXD;
}

// ================================================================= K1
// bid < 512        : embed GEMM tile (fp32 compute, fp16 out)
// 512 <= bid < 608 : pack Wq|Wk|Wv -> Wpt[c][f] fp16 transposed
// bid >= 608       : csr rows [0, CSR1)
__global__ __launch_bounds__(256) void k_front1(
        const int* __restrict__ x, const int* __restrict__ cue,
        const float* __restrict__ adj, const float* __restrict__ emb,
        const float* __restrict__ Wh, const float* __restrict__ bh,
        const float* __restrict__ Wq, const float* __restrict__ Wk,
        const float* __restrict__ Wv,
        hf* __restrict__ hB, hf* __restrict__ Wpt,
        int* __restrict__ deg, int* __restrict__ nbr) {
    __shared__ float As[32 * 64];
    __shared__ float Ws[32 * 128];
    int bid = blockIdx.x;
    int t = threadIdx.x;

    if (bid < 512) {
        int row0 = (bid >> 1) * 64, col0 = (bid & 1) * 128;
        int srow = t & 63, skg = t >> 6;
        int swc = (t & 31) * 4, swk = t >> 5;
        int tx = t & 15, ty = t >> 4;
        int xr = x[row0 + srow];
        float cv = (float)cue[row0 + srow];
        const float* er = emb + (size_t)xr * 255;

        float acc[4][8];
#pragma unroll
        for (int i = 0; i < 4; ++i)
#pragma unroll
            for (int j = 0; j < 8; ++j) acc[i][j] = 0.f;

        for (int kc = 0; kc < 256; kc += 32) {
            int kb = skg * 8;
#pragma unroll
            for (int u = 0; u < 8; ++u) {
                int f = kc + kb + u;
                As[(kb + u) * 64 + srow] = (f < 255) ? er[f] : cv;
            }
#pragma unroll
            for (int r = 0; r < 4; ++r) {
                int kk = swk + r * 8;
                f4 w = *(const f4*)(Wh + (size_t)(kc + kk) * 256 + col0 + swc);
                *(f4*)&Ws[kk * 128 + swc] = w;
            }
            __syncthreads();
#pragma unroll
            for (int k = 0; k < 32; ++k) {
                f4 av = *(f4*)&As[k * 64 + ty * 4];
                f4 w0 = *(f4*)&Ws[k * 128 + tx * 8];
                f4 w1 = *(f4*)&Ws[k * 128 + tx * 8 + 4];
                float a[4] = {av.x, av.y, av.z, av.w};
                float w[8] = {w0.x, w0.y, w0.z, w0.w, w1.x, w1.y, w1.z, w1.w};
#pragma unroll
                for (int i = 0; i < 4; ++i)
#pragma unroll
                    for (int j = 0; j < 8; ++j) acc[i][j] += a[i] * w[j];
            }
            __syncthreads();
        }
        f4 b0 = *(const f4*)(bh + col0 + tx * 8);
        f4 b1 = *(const f4*)(bh + col0 + tx * 8 + 4);
        float bb[8] = {b0.x, b0.y, b0.z, b0.w, b1.x, b1.y, b1.z, b1.w};
#pragma unroll
        for (int i = 0; i < 4; ++i) {
            int row = row0 + ty * 4 + i;
            hx8 o;
#pragma unroll
            for (int j = 0; j < 8; ++j) o[j] = (hf)fmaxf(acc[i][j] + bb[j], 0.f);
            *(hx8*)(hB + (size_t)row * 256 + col0 + tx * 8) = o;
        }
        return;
    }

    if (bid < 608) {
        int base = (bid - 512) * 256 + t;
#pragma unroll
        for (int r = 0; r < 4; ++r) {
            int i = base + r * 96 * 256;
            int c = i >> 8, f = i & 255;
            float v;
            if (c < 64)       v = Wq[f * 64 + c];
            else if (c < 128) v = Wk[f * 64 + (c - 64)];
            else              v = Wv[f * 256 + (c - 128)];
            Wpt[i] = (hf)v;
        }
        return;
    }

    csr_row(adj, deg, nbr, bid - 608, t, (int*)As);
}

// ================================================================= K2
// bid < 768 : qkv layer-1 MFMA tile (64x128, LDS-staged) — hidden under csr
// bid >= 768: csr rows [CSR1, 16384)
union QSMem {
    struct { u16 As[64 * 40]; u16 Bs[128 * 40]; } q;   // 15360 B
    int cnt;
};

__device__ __forceinline__ void qkv_tile(const hf* __restrict__ hB,
                                         const hf* __restrict__ Wpt,
                                         hf* __restrict__ qkvB,
                                         int tile, int t, QSMem& sm) {
    int col0 = (tile % 3) * 128, row0 = (tile / 3) * 64;
    int wave = t >> 6, lane = t & 63;
    int l16 = lane & 15, quad = lane >> 4;
    f4 acc[4][2];
#pragma unroll
    for (int i = 0; i < 4; ++i) { acc[i][0] = (f4){0,0,0,0}; acc[i][1] = (f4){0,0,0,0}; }
    int ar = t >> 2, ao = (t & 3) * 8;
    int bcs = t >> 1, bo = (t & 1) * 16;
    const u16* hB16 = (const u16*)hB;
    const u16* Wp16 = (const u16*)Wpt;

    for (int kc = 0; kc < 256; kc += 32) {
        us8 av  = *(const us8*)(hB16 + (size_t)(row0 + ar) * 256 + kc + ao);
        us8 bv0 = *(const us8*)(Wp16 + (size_t)(col0 + bcs) * 256 + kc + bo);
        us8 bv1 = *(const us8*)(Wp16 + (size_t)(col0 + bcs) * 256 + kc + bo + 8);
        __syncthreads();               // prior iter frag reads done
        *(us8*)&sm.q.As[ar * 40 + ao] = av;
        *(us8*)&sm.q.Bs[bcs * 40 + bo] = bv0;
        *(us8*)&sm.q.Bs[bcs * 40 + bo + 8] = bv1;
        __syncthreads();
        hx8 afr[4], bfr[2];
#pragma unroll
        for (int mt = 0; mt < 4; ++mt)
            afr[mt] = *(hx8*)&sm.q.As[(mt * 16 + l16) * 40 + quad * 8];
#pragma unroll
        for (int nt = 0; nt < 2; ++nt)
            bfr[nt] = *(hx8*)&sm.q.Bs[((wave * 2 + nt) * 16 + l16) * 40 + quad * 8];
#pragma unroll
        for (int mt = 0; mt < 4; ++mt)
#pragma unroll
            for (int nt = 0; nt < 2; ++nt)
                acc[mt][nt] = __builtin_amdgcn_mfma_f32_16x16x32_f16(
                    afr[mt], bfr[nt], acc[mt][nt], 0, 0, 0);
    }
#pragma unroll
    for (int mt = 0; mt < 4; ++mt)
#pragma unroll
        for (int nt = 0; nt < 2; ++nt) {
            int c = col0 + (wave * 2 + nt) * 16 + l16;
#pragma unroll
            for (int reg = 0; reg < 4; ++reg) {
                int r = row0 + mt * 16 + quad * 4 + reg;
                qkvB[(size_t)r * 384 + c] = (hf)acc[mt][nt][reg];
            }
        }
}

__global__ __launch_bounds__(256) void k_qkv_csr(const hf* __restrict__ hB,
                                                 const hf* __restrict__ Wpt,
                                                 hf* __restrict__ qkvB,
                                                 const float* __restrict__ adj,
                                                 int* __restrict__ deg,
                                                 int* __restrict__ nbr) {
    __shared__ QSMem sm;
    int bid = blockIdx.x, t = threadIdx.x;
    if (bid < 768) qkv_tile(hB, Wpt, qkvB, bid, t, sm);
    else           csr_row(adj, deg, nbr, CSR1 + (bid - 768), t, &sm.cnt);
}

// ---- qkv layer 2 (pure)
__global__ __launch_bounds__(256) void k_qkv(const hf* __restrict__ hB,
                                             const hf* __restrict__ Wpt,
                                             hf* __restrict__ qkvB) {
    __shared__ QSMem sm;
    qkv_tile(hB, Wpt, qkvB, blockIdx.x, threadIdx.x, sm);
}

// ========================================================= sparse attention
// One wave per row. Phase 1: quad-per-edge logits (16 edges/pass, all
// k-gathers independent). Phase 2: exact 64-lane softmax, pre-normalized
// weights (wn=0 for inactive lanes -> maskless AV). Phase 3: AV with ALL
// v-gathers independent (weights known up front). Low VGPR pressure.
template <bool WRITE_OUT>
__global__ __launch_bounds__(256) void k_attn(const hf* __restrict__ qkvB,
                                              const int* __restrict__ deg,
                                              const int* __restrict__ nbr,
                                              const float* __restrict__ gcb,
                                              const float* __restrict__ Wc,
                                              const float* __restrict__ bc,
                                              hf* __restrict__ hB,
                                              float* __restrict__ out) {
    int wave = threadIdx.x >> 6;
    int lane = threadIdx.x & 63;
    int bid = blockIdx.x;
    int row = (bid & 7) * NN + (bid >> 3) * 4 + wave;   // XCD-affine batch
    int d = deg[row];
    f4 g4 = *(const f4*)(gcb + lane * 4);
    float h0, h1, h2c, h3;
    if (d == 0) {
        h0 = sigmoidf_(g4.x); h1 = sigmoidf_(g4.y);
        h2c = sigmoidf_(g4.z); h3 = sigmoidf_(g4.w);
    } else {
        const int* jl = nbr + (size_t)row * MAXD;
        int bbase = row & ~(NN - 1);
        int jlane = jl[lane < d ? lane : 0];
        int sub = lane & 3;

        // ---- phase 1: logits, quad per edge, 16 edges per pass
        const uint4* qp = (const uint4*)(qkvB + (size_t)row * 384 + sub * 16);
        uint4 qa = qp[0], qb = qp[1];    // this lane's quarter of q (16 fp16)
        float pp[4] = {-1e30f, -1e30f, -1e30f, -1e30f};
#pragma unroll
        for (int pi = 0; pi < 4; ++pi) {
            if (pi * 16 < d) {
                int e = pi * 16 + (lane >> 2);
                int j = __shfl(jlane, e < d ? e : 0);
                float p = -1e30f;
                if (e < d) {
                    const uint4* kp = (const uint4*)(qkvB + (size_t)(bbase + j) * 384 + 64 + sub * 16);
                    uint4 ka = kp[0], kb = kp[1];
                    p = dot2_(u2h(ka.x), u2h(qa.x),
                        dot2_(u2h(ka.y), u2h(qa.y),
                        dot2_(u2h(ka.z), u2h(qa.z),
                        dot2_(u2h(ka.w), u2h(qa.w),
                        dot2_(u2h(kb.x), u2h(qb.x),
                        dot2_(u2h(kb.y), u2h(qb.y),
                        dot2_(u2h(kb.z), u2h(qb.z),
                        dot2_(u2h(kb.w), u2h(qb.w), 0.f))))))));
                }
                p += __shfl_xor(p, 1);
                p += __shfl_xor(p, 2);
                pp[pi] = p;
            }
        }
        // rearrange: lane l <- logit of edge l (source: pass l>>4, lane 4*(l&15))
        int src = (lane & 15) << 2;
        float t0 = __shfl(pp[0], src), t1 = __shfl(pp[1], src);
        float t2 = __shfl(pp[2], src), t3 = __shfl(pp[3], src);
        int hi = lane >> 4;
        float pe = hi == 0 ? t0 : hi == 1 ? t1 : hi == 2 ? t2 : t3;
        if (lane >= d) pe = -1e30f;

        // ---- phase 2: exact softmax across the wave, pre-normalized
        float mx = pe;
#pragma unroll
        for (int off = 32; off; off >>= 1) mx = fmaxf(mx, __shfl_xor(mx, off));
        float wv = __expf(pe - mx);      // 0 for inactive lanes
        float sv = wv;
#pragma unroll
        for (int off = 32; off; off >>= 1) sv += __shfl_xor(sv, off);
        float wn = wv * (1.f / sv);      // normalized weight, 0 beyond d

        // ---- phase 3: AV — all gathers independent, dot2/perm packed math
        f4 a = {0, 0, 0, 0};
        for (int g = 0; g < d; g += 4) {
            float w0 = __shfl(wn, g),     w1 = __shfl(wn, g + 1);
            float w2 = __shfl(wn, g + 2), w3 = __shfl(wn, g + 3);
            int j0 = __shfl(jlane, g),     j1 = __shfl(jlane, g + 1);
            int j2 = __shfl(jlane, g + 2), j3 = __shfl(jlane, g + 3);
            hx2 w01, w23;
            w01.x = (hf)w0; w01.y = (hf)w1;
            w23.x = (hf)w2; w23.y = (hf)w3;
            uint2 v0 = *(const uint2*)(qkvB + (size_t)(bbase + j0) * 384 + 128 + lane * 4);
            uint2 v1 = *(const uint2*)(qkvB + (size_t)(bbase + j1) * 384 + 128 + lane * 4);
            uint2 v2 = *(const uint2*)(qkvB + (size_t)(bbase + j2) * 384 + 128 + lane * 4);
            uint2 v3 = *(const uint2*)(qkvB + (size_t)(bbase + j3) * 384 + 128 + lane * 4);
            a.x = dot2_(u2h(permlo_(v1.x, v0.x)), w01,
                  dot2_(u2h(permlo_(v3.x, v2.x)), w23, a.x));
            a.y = dot2_(u2h(permhi_(v1.x, v0.x)), w01,
                  dot2_(u2h(permhi_(v3.x, v2.x)), w23, a.y));
            a.z = dot2_(u2h(permlo_(v1.y, v0.y)), w01,
                  dot2_(u2h(permlo_(v3.y, v2.y)), w23, a.z));
            a.w = dot2_(u2h(permhi_(v1.y, v0.y)), w01,
                  dot2_(u2h(permhi_(v3.y, v2.y)), w23, a.w));
        }
        h0 = sigmoidf_(a.x + g4.x);      // weights pre-normalized
        h1 = sigmoidf_(a.y + g4.y);
        h2c = sigmoidf_(a.z + g4.z);
        h3 = sigmoidf_(a.w + g4.w);
    }
    if (!WRITE_OUT) {
        hx4 o; o.x = (hf)h0; o.y = (hf)h1; o.z = (hf)h2c; o.w = (hf)h3;
        *(hx4*)(hB + (size_t)row * 256 + lane * 4) = o;
    } else {
        f4 wc0 = *(const f4*)(Wc + lane * 8);
        f4 wc1 = *(const f4*)(Wc + lane * 8 + 4);
        float pa = h0 * wc0.x + h1 * wc0.z + h2c * wc1.x + h3 * wc1.z;
        float pb = h0 * wc0.y + h1 * wc0.w + h2c * wc1.y + h3 * wc1.w;
#pragma unroll
        for (int off = 32; off; off >>= 1) {
            pa += __shfl_xor(pa, off);
            pb += __shfl_xor(pb, off);
        }
        if (lane == 0) {
            float l0 = pa + bc[0], l1 = pb + bc[1];
            float m2 = fmaxf(l0, l1);
            float e0 = __expf(l0 - m2), e1 = __expf(l1 - m2);
            float inv2 = 1.f / (e0 + e1);
            out[(size_t)row * 2 + 0] = e0 * inv2;
            out[(size_t)row * 2 + 1] = e1 * inv2;
        }
    }
}

extern "C" void kernel_launch(void* const* d_in, const int* in_sizes, int n_in,
                              void* d_out, int out_size, void* d_ws, size_t ws_size,
                              hipStream_t stream) {
    const int*   x    = (const int*)d_in[0];
    const int*   cue  = (const int*)d_in[1];
    const float* adj  = (const float*)d_in[2];
    const float* emb  = (const float*)d_in[3];
    const float* Wh   = (const float*)d_in[4];
    const float* bh   = (const float*)d_in[5];
    const float* Wq   = (const float*)d_in[6];
    const float* Wk   = (const float*)d_in[7];
    const float* Wv   = (const float*)d_in[8];
    const float* gcb  = (const float*)d_in[9];
    const float* Wc   = (const float*)d_in[10];
    const float* bc   = (const float*)d_in[11];
    float* out = (float*)d_out;

    // workspace carve (~24.3 MB)
    char* w = (char*)d_ws;
    hf*  hB   = (hf*)w;   w += (size_t)ROWS * 256 * 2;   // 8 MB
    hf*  qkvB = (hf*)w;   w += (size_t)ROWS * 384 * 2;   // 12 MB
    hf*  Wpt  = (hf*)w;   w += (size_t)384 * 256 * 2;    // 192 KB
    int* deg  = (int*)w;  w += (size_t)ROWS * 4;         // 64 KB
    int* nbr  = (int*)w;                                  // 4 MB

    // K1: embed + pack + csr[0,CSR1)
    k_front1<<<608 + CSR1, 256, 0, stream>>>(
        x, cue, adj, emb, Wh, bh, Wq, Wk, Wv, hB, Wpt, deg, nbr);
    // K2: qkv layer 1 (hidden under csr[CSR1,16384))
    k_qkv_csr<<<768 + (ROWS - CSR1), 256, 0, stream>>>(hB, Wpt, qkvB, adj, deg, nbr);
    // K3: attn layer 1
    k_attn<false><<<ROWS / 4, 256, 0, stream>>>(qkvB, deg, nbr, gcb, Wc, bc, hB, out);
    // K4: qkv layer 2
    k_qkv<<<768, 256, 0, stream>>>(hB, Wpt, qkvB);
    // K5: attn layer 2 + classifier head
    k_attn<true><<<ROWS / 4, 256, 0, stream>>>(qkvB, deg, nbr, gcb, Wc, bc, hB, out);
}